// Round 7
// baseline (320.525 us; speedup 1.0000x reference)
//
#include <hip/hip_runtime.h>
#include <hip/hip_fp16.h>
#include <math.h>

#define LUT_D 33
#define LUT_D3 35937   // 33^3
#define NEG 0.2f
#define BATCH 4
#define HW_IMG 1048576 // 1024*1024

// ---------------- resize 1024 -> 256: block = one output row, LDS-staged coalesced ---------
__global__ void __launch_bounds__(256) k_resize(const float* __restrict__ lq,
                                                float* __restrict__ out) {
    __shared__ float row0[1024], row1[1024];
    int y  = blockIdx.x & 255;
    int pc = blockIdx.x >> 8;                      // b*3 + c
    const float* in = lq + (size_t)pc * HW_IMG;
    const float4* r0 = (const float4*)(in + (4 * y + 1) * 1024);
    const float4* r1 = (const float4*)(in + (4 * y + 2) * 1024);
    int t = threadIdx.x;
    ((float4*)row0)[t] = r0[t];
    ((float4*)row1)[t] = r1[t];
    int t2 = t + 256;
    if (t2 < 256) {} // keep structure simple
    ((float4*)row0)[t] = r0[t];   // 256 threads x 1 float4 = 1024 floats? need 256 f4 = 1024 floats ✓
    ((float4*)row1)[t] = r1[t];
    __syncthreads();
    float4 a = *(const float4*)(row0 + 4 * t);
    float4 b = *(const float4*)(row1 + 4 * t);
    out[(size_t)pc * 65536 + y * 256 + t] = 0.25f * (a.y + a.z + b.y + b.z);
}

// ---------------- tiled conv3x3 s2 p1 (+LeakyReLU if NSPLIT==1), fused input-norm -----------
template<int IC, int OC, int OH, int OW, int NSPLIT, bool NORM_IN, bool STATS_OUT>
__global__ void __launch_bounds__(256) k_conv_t(
    const float* __restrict__ in, const float* __restrict__ nrm_in,
    const float* __restrict__ w, const float* __restrict__ bias,
    float* __restrict__ out, float* __restrict__ part) {
    constexpr int IH = OH * 2, IW = OW * 2;
    constexpr int ICB = IC / NSPLIT;              // <= 32
    constexpr int TROW = 20, TSZ = 17 * TROW;     // 340 floats per ic tile
    constexpr int WQ = ICB * 9 / 4;               // float4s per oc slice
    constexpr int NTX = OW / 8, NTY = OH / 8, NOCG = OC / 16;
    constexpr int NT = NTX * NTY;
    constexpr int PX = OH * OW;

    __shared__ float sIn[ICB * TSZ];
    __shared__ float swl[16 * ICB * 9];
    __shared__ float sNm[NORM_IN ? ICB * 2 : 1];

    int id = blockIdx.x;
    int ocg   = id % NOCG;   id /= NOCG;
    int icc_i = id % NSPLIT; id /= NSPLIT;
    int tx    = id % NTX;    id /= NTX;
    int ty    = id % NTY;    id /= NTY;
    int b     = id;
    int icc   = icc_i * ICB;

    int t    = threadIdx.x;
    int lane = t >> 6;          // 0..3
    int px   = t & 63;
    int py   = px >> 3, pxx = px & 7;
    int oc0  = ocg * 16 + lane * 4;

    if (IC == ICB) {
        const float4* wsrc = (const float4*)(w + (size_t)ocg * 16 * IC * 9);
        for (int i = t; i < 16 * IC * 9 / 4; i += 256) ((float4*)swl)[i] = wsrc[i];
    } else {
        for (int i = t; i < 16 * WQ; i += 256) {
            int ol = i / WQ, qi = i % WQ;
            ((float4*)swl)[ol * WQ + qi] =
                *(const float4*)(w + ((size_t)(ocg * 16 + ol) * IC + icc) * 9 + qi * 4);
        }
    }
    if (NORM_IN) {
        for (int i = t; i < ICB * 2; i += 256) sNm[i] = nrm_in[(b * IC + icc) * 2 + i];
    }
    __syncthreads();

    int iy0 = ty * 16 - 1;
    int xbase = tx * 16;
    const float* inb = in + (size_t)(b * IC + icc) * (IH * IW);
    for (int q = t; q < ICB * 17 * 4; q += 256) {
        int ic_l = q / 68;
        int r    = q % 68;
        int row  = r >> 2, quad = r & 3;
        int iy = iy0 + row;
        float4 v = {0.f, 0.f, 0.f, 0.f};
        if (iy >= 0 && iy < IH) {
            v = *(const float4*)(inb + (size_t)ic_l * (IH * IW) + (size_t)iy * IW + xbase + quad * 4);
            if (NORM_IN) {
                float sc = sNm[ic_l * 2], sh = sNm[ic_l * 2 + 1];
                v.x = v.x * sc + sh; v.y = v.y * sc + sh;
                v.z = v.z * sc + sh; v.w = v.w * sc + sh;
            }
        }
        *(float4*)(sIn + ic_l * TSZ + row * TROW + 4 + quad * 4) = v;
    }
    for (int h = t; h < ICB * 17; h += 256) {
        int ic_l = h / 17, row = h % 17;
        int iy = iy0 + row, ix = xbase - 1;
        float v = 0.f;
        if (iy >= 0 && iy < IH && ix >= 0) {
            v = inb[(size_t)ic_l * (IH * IW) + (size_t)iy * IW + ix];
            if (NORM_IN) v = v * sNm[ic_l * 2] + sNm[ic_l * 2 + 1];
        }
        sIn[ic_l * TSZ + row * TROW + 3] = v;
    }
    __syncthreads();

    float acc[4];
    #pragma unroll
    for (int j = 0; j < 4; j++) acc[j] = (NSPLIT == 1) ? bias[oc0 + j] : 0.f;

    for (int i2 = 0; i2 < ICB; i2++) {
        const float* tp = sIn + i2 * TSZ + py * 2 * TROW + pxx * 2 + 3;
        float x0 = tp[0],        x1 = tp[1],        x2 = tp[2];
        float x3 = tp[TROW],     x4 = tp[TROW + 1], x5 = tp[TROW + 2];
        float x6 = tp[2 * TROW], x7 = tp[2 * TROW + 1], x8 = tp[2 * TROW + 2];
        #pragma unroll
        for (int j = 0; j < 4; j++) {
            const float* wp = swl + ((lane * 4 + j) * ICB + i2) * 9;
            acc[j] = fmaf(x0, wp[0], acc[j]);
            acc[j] = fmaf(x1, wp[1], acc[j]);
            acc[j] = fmaf(x2, wp[2], acc[j]);
            acc[j] = fmaf(x3, wp[3], acc[j]);
            acc[j] = fmaf(x4, wp[4], acc[j]);
            acc[j] = fmaf(x5, wp[5], acc[j]);
            acc[j] = fmaf(x6, wp[6], acc[j]);
            acc[j] = fmaf(x7, wp[7], acc[j]);
            acc[j] = fmaf(x8, wp[8], acc[j]);
        }
    }

    int oy = ty * 8 + py, ox = tx * 8 + pxx;
    if (NSPLIT == 1) {
        int tile = ty * NTX + tx;
        #pragma unroll
        for (int j = 0; j < 4; j++) {
            float a = acc[j];
            a = a >= 0.f ? a : NEG * a;
            out[((size_t)(b * OC + oc0 + j) * OH + oy) * OW + ox] = a;
            if (STATS_OUT) {
                float s1 = a, s2 = a * a;
                for (int off = 32; off > 0; off >>= 1) {
                    s1 += __shfl_down(s1, off, 64);
                    s2 += __shfl_down(s2, off, 64);
                }
                if (px == 0) {
                    size_t pi = ((size_t)(b * OC + oc0 + j) * NT + tile) * 2;
                    part[pi] = s1; part[pi + 1] = s2;
                }
            }
        }
    } else {
        #pragma unroll
        for (int j = 0; j < 4; j++) {
            part[(size_t)icc_i * (BATCH * OC * PX) +
                 (size_t)(b * OC + oc0 + j) * PX + oy * OW + ox] = acc[j];
        }
    }
}

// ---------------- combine ic-split partials: + bias, LeakyReLU, optional stats -------------
template<int NSPLIT, int OC, int PX, bool STATS>
__global__ void k_combine(const float* __restrict__ ps, const float* __restrict__ bias,
                          float* __restrict__ out, float* __restrict__ spart) {
    constexpr int TOT = BATCH * OC * PX;
    int e = blockIdx.x * 256 + threadIdx.x;
    if (e >= TOT) return;
    float s = 0.f;
    #pragma unroll
    for (int k = 0; k < NSPLIT; k++) s += ps[(size_t)k * TOT + e];
    int oc = (e / PX) % OC;
    s += bias[oc];
    s = s >= 0.f ? s : NEG * s;
    out[e] = s;
    if (STATS) {
        float s1 = s, s2 = s * s;
        for (int off = 32; off > 0; off >>= 1) {
            s1 += __shfl_down(s1, off, 64);
            s2 += __shfl_down(s2, off, 64);
        }
        if ((threadIdx.x & 63) == 0) {
            int widx = e >> 6;
            spart[widx * 2] = s1; spart[widx * 2 + 1] = s2;
        }
    }
}

// ---------------- reduce partial (s1,s2) -> per-(b,c) norm pair (scale, shift) -------------
template<int NT>
__global__ void k_norm(const float* __restrict__ part, const float* __restrict__ g,
                       const float* __restrict__ be, float invN, int C,
                       float* __restrict__ nrm) {
    int bc = blockIdx.x;
    int t  = threadIdx.x;  // 64
    float s1 = 0.f, s2 = 0.f;
    for (int i = t; i < NT; i += 64) {
        s1 += part[((size_t)bc * NT + i) * 2];
        s2 += part[((size_t)bc * NT + i) * 2 + 1];
    }
    #pragma unroll
    for (int off = 32; off > 0; off >>= 1) {
        s1 += __shfl_down(s1, off, 64);
        s2 += __shfl_down(s2, off, 64);
    }
    if (t == 0) {
        int c = bc % C;
        float m   = s1 * invN;
        float var = s2 * invN - m * m;
        float sc  = g[c] * rsqrtf(var + 1e-5f);
        nrm[bc * 2]     = sc;
        nrm[bc * 2 + 1] = be[c] - m * sc;
    }
}

// ---------------- AdaptiveAvgPool2d(2) on [4,128,8,8] -> codes [4,512] ---------------------
__global__ void k_pool(const float* __restrict__ f5, float* __restrict__ codes) {
    int c = blockIdx.x * 256 + threadIdx.x;   // 2048
    if (c >= 2048) return;
    int b = c >> 9;
    int rest = c & 511;
    int oc = rest >> 2, q = rest & 3;
    int py = (q >> 1) * 4, px = (q & 1) * 4;
    const float* p = f5 + ((size_t)(b * 128 + oc)) * 64;
    float s = 0.f;
    #pragma unroll
    for (int dy = 0; dy < 4; dy++)
        #pragma unroll
        for (int dx = 0; dx < 4; dx++)
            s += p[(py + dy) * 8 + px + dx];
    codes[c] = s * (1.f / 16.f);
}

// ---------------- heads + inverse-search hint table ----------------------------------------
// blocks 0..11: (b,ch): intervals -> softmax -> cumsum -> vertices + hint[1024] (uchar)
// block 12: the 12 lut-weights
__global__ void k_head(const float* __restrict__ codes, const float* __restrict__ lw,
                       const float* __restrict__ lb, const float* __restrict__ aw,
                       const float* __restrict__ ab, float* __restrict__ wt,
                       float* __restrict__ vert, unsigned char* __restrict__ hint,
                       float* __restrict__ out_w, float* __restrict__ out_v) {
    int blk = blockIdx.x;
    int t = threadIdx.x;  // 64 threads
    if (blk == 12) {
        if (t < 12) {
            int b = t / 3, j = t % 3;
            const float* c = codes + b * 512;
            const float* l = lw + j * 512;
            float s = lb[j];
            for (int k = 0; k < 512; k++) s += c[k] * l[k];
            wt[t] = s;
            out_w[t] = s;
        }
        return;
    }
    int b = blk / 3, ch = blk % 3;
    __shared__ float y[32];
    __shared__ float sve[33];
    if (t < 32) {
        const float* c = codes + b * 512;
        const float* a = aw + (size_t)(ch * 32 + t) * 512;
        float s = ab[ch * 32 + t];
        for (int k = 0; k < 512; k++) s += c[k] * a[k];
        y[t] = s;
    }
    __syncthreads();
    if (t == 0) {
        float mx = y[0];
        for (int m = 1; m < 32; m++) mx = fmaxf(mx, y[m]);
        float e[32];
        float sum = 0.f;
        for (int m = 0; m < 32; m++) { e[m] = expf(y[m] - mx); sum += e[m]; }
        float inv = 1.f / sum;
        float cum = 0.f;
        float* vb = vert + (b * 3 + ch) * 33;
        float* ob = out_v + (b * 3 + ch) * 33;
        vb[0] = 0.f; ob[0] = 0.f; sve[0] = 0.f;
        for (int m = 0; m < 32; m++) {
            cum += e[m] * inv;
            vb[m + 1] = cum; ob[m + 1] = cum; sve[m + 1] = cum;
        }
    }
    __syncthreads();
    unsigned char* hb = hint + (size_t)(b * 3 + ch) * 1024;
    for (int i = t; i < 1024; i += 64) {
        float xl = (float)i * (1.f / 1024.f);
        int lo = 0, hi = LUT_D;
        while (lo < hi) { int mid = (lo + hi) >> 1; if (sve[mid] <= xl) lo = mid + 1; else hi = mid; }
        hb[i] = (unsigned char)lo;   // searchsorted_right(v, xl), in [1,33]
    }
}

// ---------------- LUT generation: fp16 blue-pair entries ------------------------------------
__global__ void k_lutgen(const float* __restrict__ bw, const float* __restrict__ wt,
                         float4* __restrict__ lutp) {
    int gid = blockIdx.x * 256 + threadIdx.x;     // over 4*35937
    if (gid >= BATCH * LUT_D3) return;
    int b = gid / LUT_D3;
    int cell = gid - b * LUT_D3;
    int k = cell % LUT_D;
    int cn = (k < LUT_D - 1) ? cell + 1 : cell;
    float w0 = wt[b * 3], w1 = wt[b * 3 + 1], w2 = wt[b * 3 + 2];
    const float* r0p = bw + (size_t)(0 * LUT_D3 + cell) * 3;
    const float* g0p = bw + (size_t)(1 * LUT_D3 + cell) * 3;
    const float* b0p = bw + (size_t)(2 * LUT_D3 + cell) * 3;
    const float* r1p = bw + (size_t)(0 * LUT_D3 + cn) * 3;
    const float* g1p = bw + (size_t)(1 * LUT_D3 + cn) * 3;
    const float* b1p = bw + (size_t)(2 * LUT_D3 + cn) * 3;
    union { float4 f4; __half h[8]; } u;
    u.h[0] = __float2half_rn(r0p[0] * w0 + r0p[1] * w1 + r0p[2] * w2);
    u.h[1] = __float2half_rn(g0p[0] * w0 + g0p[1] * w1 + g0p[2] * w2);
    u.h[2] = __float2half_rn(b0p[0] * w0 + b0p[1] * w1 + b0p[2] * w2);
    u.h[3] = __float2half_rn(r1p[0] * w0 + r1p[1] * w1 + r1p[2] * w2);
    u.h[4] = __float2half_rn(g1p[0] * w0 + g1p[1] * w1 + g1p[2] * w2);
    u.h[5] = __float2half_rn(b1p[0] * w0 + b1p[1] * w1 + b1p[2] * w2);
    u.h[6] = __float2half_rn(0.f);
    u.h[7] = __float2half_rn(0.f);
    lutp[gid] = u.f4;
}

// ---------------- per-pixel hint-search + trilinear LUT sample -----------------------------
__device__ __forceinline__ int searchh(const float* __restrict__ sv,
                                       const unsigned char* __restrict__ sh,
                                       int ch, float x, float& f) {
    int bin = (int)(x * 1024.f);
    bin = bin < 0 ? 0 : (bin > 1023 ? 1023 : bin);
    int h = sh[ch * 1024 + bin];
    const float* v = sv + ch * LUT_D;
    while (h < LUT_D && v[h] <= x) h++;          // rare advance
    int idx = h < 1 ? 1 : (h > LUT_D - 1 ? LUT_D - 1 : h);
    float vl = v[idx - 1], vh = v[idx];
    float fr = (x - vl) / (vh - vl + 1e-8f);
    float coord = (float)(idx - 1) + fr;
    coord = fminf(fmaxf(coord, 0.f), (float)(LUT_D - 1));
    int i0 = (int)floorf(coord);
    if (i0 > LUT_D - 2) i0 = LUT_D - 2;
    f = coord - (float)i0;
    return i0;
}

__device__ __forceinline__ void decode_lerp(float4 e, float fb,
                                            float& rv, float& gv, float& bv) {
    union { float f; __half2 h; } u0, u1, u2;
    u0.f = e.x; u1.f = e.y; u2.f = e.z;
    float2 a = __half22float2(u0.h);   // r0, g0
    float2 b = __half22float2(u1.h);   // b0, r1
    float2 c = __half22float2(u2.h);   // g1, b1
    rv = fmaf(fb, b.y - a.x, a.x);
    gv = fmaf(fb, c.x - a.y, a.y);
    bv = fmaf(fb, c.y - b.x, b.x);
}

__global__ void __launch_bounds__(256) k_transform(const float* __restrict__ lq,
                                                   const float4* __restrict__ lutp,
                                                   const float* __restrict__ vert,
                                                   const unsigned char* __restrict__ hintg,
                                                   float* __restrict__ out) {
    int bimg = blockIdx.x >> 10;                  // 1024 blocks per image
    int blk  = blockIdx.x & 1023;
    __shared__ float sv[3 * LUT_D];
    __shared__ unsigned char sh[3 * 1024];
    if (threadIdx.x < 3 * LUT_D) sv[threadIdx.x] = vert[bimg * 3 * LUT_D + threadIdx.x];
    for (int i = threadIdx.x; i < 768; i += 256)
        ((unsigned int*)sh)[i] = ((const unsigned int*)hintg)[bimg * 768 + i];
    __syncthreads();
    int p0 = blk * 1024 + threadIdx.x * 4;        // 4 px per thread
    const float* lr = lq + (size_t)bimg * 3 * HW_IMG + p0;
    float4 r4 = *(const float4*)(lr);
    float4 g4 = *(const float4*)(lr + HW_IMG);
    float4 b4 = *(const float4*)(lr + 2 * HW_IMG);
    const float4* L = lutp + (size_t)bimg * LUT_D3;
    float rr[4] = {r4.x, r4.y, r4.z, r4.w};
    float gg[4] = {g4.x, g4.y, g4.z, g4.w};
    float bb[4] = {b4.x, b4.y, b4.z, b4.w};

    // phase A: searches
    int base[4];
    float fr[4], fg[4], fb[4];
    #pragma unroll
    for (int i = 0; i < 4; i++) {
        float f0, f1, f2;
        int i0 = searchh(sv, sh, 0, rr[i], f0);
        int j0 = searchh(sv, sh, 1, gg[i], f1);
        int k0 = searchh(sv, sh, 2, bb[i], f2);
        base[i] = (i0 * LUT_D + j0) * LUT_D + k0;
        fr[i] = f0; fg[i] = f1; fb[i] = f2;
    }
    // phase B: issue all 16 gathers
    float4 e00[4], e01[4], e10[4], e11[4];
    #pragma unroll
    for (int i = 0; i < 4; i++) {
        e00[i] = L[base[i]];
        e01[i] = L[base[i] + 33];
        e10[i] = L[base[i] + 1089];
        e11[i] = L[base[i] + 1122];
    }
    // phase C: decode + bilinear
    float ro[4], go[4], bo[4];
    #pragma unroll
    for (int i = 0; i < 4; i++) {
        float r00, g00, b00, r01, g01, b01, r10, g10, b10, r11, g11, b11;
        decode_lerp(e00[i], fb[i], r00, g00, b00);
        decode_lerp(e01[i], fb[i], r01, g01, b01);
        decode_lerp(e10[i], fb[i], r10, g10, b10);
        decode_lerp(e11[i], fb[i], r11, g11, b11);
        float w00 = (1.f - fr[i]) * (1.f - fg[i]), w01 = (1.f - fr[i]) * fg[i];
        float w10 = fr[i] * (1.f - fg[i]),         w11 = fr[i] * fg[i];
        float rx = r00 * w00 + r01 * w01 + r10 * w10 + r11 * w11;
        float ry = g00 * w00 + g01 * w01 + g10 * w10 + g11 * w11;
        float rz = b00 * w00 + b01 * w01 + b10 * w10 + b11 * w11;
        ro[i] = fminf(fmaxf(rx, 0.f), 1.f);
        go[i] = fminf(fmaxf(ry, 0.f), 1.f);
        bo[i] = fminf(fmaxf(rz, 0.f), 1.f);
    }
    float* op = out + (size_t)bimg * 3 * HW_IMG + p0;
    float4 o0 = {ro[0], ro[1], ro[2], ro[3]};
    float4 o1 = {go[0], go[1], go[2], go[3]};
    float4 o2 = {bo[0], bo[1], bo[2], bo[3]};
    *(float4*)(op) = o0;
    *(float4*)(op + HW_IMG) = o1;
    *(float4*)(op + 2 * HW_IMG) = o2;
}

extern "C" void kernel_launch(void* const* d_in, const int* in_sizes, int n_in,
                              void* d_out, int out_size, void* d_ws, size_t ws_size,
                              hipStream_t stream) {
    const float* lq  = (const float*)d_in[0];
    const float* w1  = (const float*)d_in[1];
    const float* b1  = (const float*)d_in[2];
    const float* g1  = (const float*)d_in[3];
    const float* be1 = (const float*)d_in[4];
    const float* w2  = (const float*)d_in[5];
    const float* b2  = (const float*)d_in[6];
    const float* g2  = (const float*)d_in[7];
    const float* be2 = (const float*)d_in[8];
    const float* w3  = (const float*)d_in[9];
    const float* b3  = (const float*)d_in[10];
    const float* g3  = (const float*)d_in[11];
    const float* be3 = (const float*)d_in[12];
    const float* w4  = (const float*)d_in[13];
    const float* b4  = (const float*)d_in[14];
    const float* g4  = (const float*)d_in[15];
    const float* be4 = (const float*)d_in[16];
    const float* w5  = (const float*)d_in[17];
    const float* b5  = (const float*)d_in[18];
    const float* lw  = (const float*)d_in[19];
    const float* lb  = (const float*)d_in[20];
    const float* bw  = (const float*)d_in[21];
    const float* aw  = (const float*)d_in[22];
    const float* ab  = (const float*)d_in[23];

    float* ws     = (float*)d_ws;
    float* r256   = ws;                    // 786432
    float* f1     = r256 + 786432;         // 1048576 (dead after S2; psplit4/5 aliased here)
    float* f2     = f1 + 1048576;          // 524288
    float* f3     = f2 + 524288;           // 262144
    float* f4     = f3 + 262144;           // 131072
    float* f5     = f4 + 131072;           // 32768 (4x128x8x8)
    float* codes  = f5 + 32768;            // 2048
    float* wt     = codes + 2048;          // 12
    float* vert   = wt + 12;               // 396
    float* part1  = vert + 396;            // 32768
    float* part2  = part1 + 32768;         // 16384
    float* part3  = part2 + 16384;         // 8192
    float* spart4 = part3 + 8192;          // 4096
    float* norm1  = spart4 + 4096;         // 128
    float* norm2  = norm1 + 128;           // 256
    float* norm3  = norm2 + 256;           // 512
    float* norm4  = norm3 + 512;           // 1024
    float* hintf  = norm4 + 1024;          // 12*1024 bytes = 3072 floats
    float* luts4  = hintf + 3072;          // 4*35937 float4 entries; 16B aligned
    float* psplit4 = f1;                   // alias (f1 dead by S4)
    float* psplit5 = f1 + 262144;

    unsigned char* hint = (unsigned char*)hintf;

    float* outs  = (float*)d_out;
    float* out_w = outs + (size_t)BATCH * 3 * HW_IMG;  // 12582912
    float* out_v = out_w + 12;

    k_resize<<<BATCH * 3 * 256, 256, 0, stream>>>(lq, r256);
    // S1: [4,3,256,256] -> f1 [4,16,128,128]; grid 4*16*16*1*1 = 1024
    k_conv_t<3, 16, 128, 128, 1, false, true><<<1024, 256, 0, stream>>>(
        r256, nullptr, w1, b1, f1, part1);
    k_norm<256><<<64, 64, 0, stream>>>(part1, g1, be1, 1.f / 16384.f, 16, norm1);
    // S2: -> f2 [4,32,64,64]; grid 4*8*8*1*2 = 512
    k_conv_t<16, 32, 64, 64, 1, true, true><<<512, 256, 0, stream>>>(
        f1, norm1, w2, b2, f2, part2);
    k_norm<64><<<128, 64, 0, stream>>>(part2, g2, be2, 1.f / 4096.f, 32, norm2);
    // S3: -> f3 [4,64,32,32]; grid 4*4*4*1*4 = 256
    k_conv_t<32, 64, 32, 32, 1, true, true><<<256, 256, 0, stream>>>(
        f2, norm2, w3, b3, f3, part3);
    k_norm<16><<<256, 64, 0, stream>>>(part3, g3, be3, 1.f / 1024.f, 64, norm3);
    // S4: -> psplit4; grid 4*2*2*2*8 = 256; combine -> f4 + stats
    k_conv_t<64, 128, 16, 16, 2, true, false><<<256, 256, 0, stream>>>(
        f3, norm3, w4, b4, nullptr, psplit4);
    k_combine<2, 128, 256, true><<<512, 256, 0, stream>>>(psplit4, b4, f4, spart4);
    k_norm<4><<<512, 64, 0, stream>>>(spart4, g4, be4, 1.f / 256.f, 128, norm4);
    // S5: -> psplit5; grid 4*1*1*4*8 = 128; combine -> f5 (no IN)
    k_conv_t<128, 128, 8, 8, 4, true, false><<<128, 256, 0, stream>>>(
        f4, norm4, w5, b5, nullptr, psplit5);
    k_combine<4, 128, 64, false><<<128, 256, 0, stream>>>(psplit5, b5, f5, nullptr);
    k_pool<<<8, 256, 0, stream>>>(f5, codes);
    k_head<<<13, 64, 0, stream>>>(codes, lw, lb, aw, ab, wt, vert, hint, out_w, out_v);
    k_lutgen<<<(BATCH * LUT_D3 + 255) / 256, 256, 0, stream>>>(bw, wt, (float4*)luts4);
    k_transform<<<BATCH * 1024, 256, 0, stream>>>(lq, (const float4*)luts4, vert, hint, outs);
}